// Round 13
// baseline (776.356 us; speedup 1.0000x reference)
//
#include <hip/hip_runtime.h>
#include <hip/hip_bf16.h>
#include <stdint.h>

// QuantizedLinear: y = x @ (Wq * scale[:,None])^T + bias
// Round 13: the untested cell of the design matrix -- 256x256 / BK=128 /
// 8 waves (2Mx4N, per-wave 128x64) / ONE barrier per tile / phase-local
// frag liveness / no VGPR cap. Why this geometry: per-wave LDS-read volume
// ~ (1/Wm+1/Wn); 128x64 waves need only kappa=88 B/cyc (feasible) vs r4's
// 64x64 waves needing 147 (impossible -> r4 pinned at LDS floor, 373us).
// Prior 256-sq failures isolated: r7 mid-tile barrier (bulk drains), r8
// spills (24-frag clustered liveness + launch_bounds VGPR cap), r9 barrier
// again. Here: wave-skew INSIDE the block (no mid-tile barrier) supplies
// the overlap that 2-block TLP gave r4.
// Tile t: STAGE A,B(t+1)->bq (8 gload_lds) | RD 12 K0-frags(bp) | 32 MFMA |
//         RD 12 K1-frags(bp) | 32 MFMA | lgkm(0)[free] vmcnt(0)[2600cyc
//         cover] barrier.
// WAR: bq readers drained at t-1's lgkm(0)+barrier. RAW: bp staged at t-1
// start, drained by t-1's vmcnt(0)+barrier.

#define M_TOTAL 8192
#define K_TOTAL 4096
#define N_TOTAL 11008
#define NT 32
#define NBM 32
#define NBN 43

typedef __attribute__((ext_vector_type(4))) int int4v;

// ---------------- fused prep: x row-quant + W unpack (r12 verbatim) ----------------

__global__ __launch_bounds__(256) void prep_kernel(const float* __restrict__ x,
                                                   const int* __restrict__ wq,
                                                   signed char* __restrict__ xq,
                                                   signed char* __restrict__ wb,
                                                   float* __restrict__ sx) {
    __shared__ float wm_[4];
    if (blockIdx.x < M_TOTAL) {
        const int row = blockIdx.x;
        const int tid = threadIdx.x;
        const float* xr = x + (size_t)row * K_TOTAL + tid * 16;

        float4 v0 = reinterpret_cast<const float4*>(xr)[0];
        float4 v1 = reinterpret_cast<const float4*>(xr)[1];
        float4 v2 = reinterpret_cast<const float4*>(xr)[2];
        float4 v3 = reinterpret_cast<const float4*>(xr)[3];

        float m = 0.f;
        m = fmaxf(m, fmaxf(fmaxf(fabsf(v0.x), fabsf(v0.y)), fmaxf(fabsf(v0.z), fabsf(v0.w))));
        m = fmaxf(m, fmaxf(fmaxf(fabsf(v1.x), fabsf(v1.y)), fmaxf(fabsf(v1.z), fabsf(v1.w))));
        m = fmaxf(m, fmaxf(fmaxf(fabsf(v2.x), fabsf(v2.y)), fmaxf(fabsf(v2.z), fabsf(v2.w))));
        m = fmaxf(m, fmaxf(fmaxf(fabsf(v3.x), fabsf(v3.y)), fmaxf(fabsf(v3.z), fabsf(v3.w))));

        for (int d = 1; d < 64; d <<= 1) m = fmaxf(m, __shfl_xor(m, d));
        if ((tid & 63) == 0) wm_[tid >> 6] = m;
        __syncthreads();
        m = fmaxf(fmaxf(wm_[0], wm_[1]), fmaxf(wm_[2], wm_[3]));

        const float inv = (m > 0.f) ? (127.f / m) : 0.f;
        if (tid == 0) sx[row] = (m > 0.f) ? (m / 127.f) : 0.f;

        float tmp[16] = {v0.x,v0.y,v0.z,v0.w, v1.x,v1.y,v1.z,v1.w,
                         v2.x,v2.y,v2.z,v2.w, v3.x,v3.y,v3.z,v3.w};
        int q[16];
#pragma unroll
        for (int i = 0; i < 16; ++i) {
            int t = __float2int_rn(tmp[i] * inv);
            q[i] = t > 127 ? 127 : (t < -127 ? -127 : t);
        }
        int4v o;
#pragma unroll
        for (int w = 0; w < 4; ++w)
            o[w] = (q[w*4] & 255) | ((q[w*4+1] & 255) << 8) |
                   ((q[w*4+2] & 255) << 16) | ((q[w*4+3] & 255) << 24);
        *reinterpret_cast<int4v*>(xq + (size_t)row * K_TOTAL + tid * 16) = o;
    } else {
        const int nitems = (int)(((size_t)N_TOTAL * K_TOTAL) / 16);
        bool is8 = false;
        for (int i = 0; i < 256; ++i) {
            int v = wq[i];
            if (v < -127 || v > 127) { is8 = true; break; }
        }
        const int nblk = gridDim.x - M_TOTAL;
        const int stride = nblk * blockDim.x;
        const int start = (blockIdx.x - M_TOTAL) * blockDim.x + threadIdx.x;
        if (!is8) {
            for (int i = start; i < nitems; i += stride) {
                const int* p = wq + (size_t)i * 16;
                int4v o;
#pragma unroll
                for (int w = 0; w < 4; ++w)
                    o[w] = (p[w*4] & 255) | ((p[w*4+1] & 255) << 8) |
                           ((p[w*4+2] & 255) << 16) | ((p[w*4+3] & 255) << 24);
                *reinterpret_cast<int4v*>(wb + (size_t)i * 16) = o;
            }
        } else {
            const int4v* in16 = reinterpret_cast<const int4v*>(wq);
            for (int i = start; i < nitems; i += stride)
                *reinterpret_cast<int4v*>(wb + (size_t)i * 16) = in16[i];
        }
    }
}

// ---------------- 256x256 i8 GEMM, single-barrier, phase-split liveness ----------------

#define GLOAD16(g, l) __builtin_amdgcn_global_load_lds( \
    (const __attribute__((address_space(1))) void*)(g), \
    (__attribute__((address_space(3))) void*)(l), 16, 0, 0)

// LDS (bytes): buf p*65536 + {A: [0,32K) | B: [32K,64K)}; tile t in buf[t&1].
// chunk = 8 rows = 1 KiB; wave wv stages chunks wv*4..wv*4+3 per operand.
// Swizzle: 16B granule g stored at g ^ (row&7); inverse applied on global src.

#define RD_A8(dst, base, KX)                                                    \
    _Pragma("unroll")                                                           \
    for (int i_ = 0; i_ < 8; ++i_)                                              \
        dst[i_] = *(const int4v*)((base) + (wm * 128 + i_ * 16 + fr) * 128 + (KX));
#define RD_B4(dst, base, KX)                                                    \
    _Pragma("unroll")                                                           \
    for (int n_ = 0; n_ < 4; ++n_)                                              \
        dst[n_] = *(const int4v*)((base) + 32768 + (wn * 64 + n_ * 16 + fr) * 128 + (KX));
#define MFMA32(fa, fb)                                                          \
    __builtin_amdgcn_s_setprio(1);                                              \
    _Pragma("unroll")                                                           \
    for (int i_ = 0; i_ < 8; ++i_) {                                            \
        _Pragma("unroll")                                                       \
        for (int n_ = 0; n_ < 4; ++n_)                                          \
            acc[i_][n_] = __builtin_amdgcn_mfma_i32_16x16x64_i8(                \
                fa[i_], fb[n_], acc[i_][n_], 0, 0, 0);                          \
    }                                                                           \
    __builtin_amdgcn_s_setprio(0);
#define STAGE_A(asrc, buf)                                                      \
    _Pragma("unroll")                                                           \
    for (int i_ = 0; i_ < 4; ++i_)                                              \
        GLOAD16((asrc) + soff[i_], (buf) + (c0 + i_) * 1024);
#define STAGE_B(bsrc, buf)                                                      \
    _Pragma("unroll")                                                           \
    for (int i_ = 0; i_ < 4; ++i_)                                              \
        GLOAD16((bsrc) + soff[i_], (buf) + 32768 + (c0 + i_) * 1024);

// One tile, ONE barrier. Phase-local frag liveness (12 frags max).
#define TILE(bp, bq, tnext)                                                     \
    {                                                                           \
        if ((tnext) < NT) {                                                     \
            STAGE_A(aS + (size_t)(tnext) * 128, bq)                             \
            STAGE_B(bS + (size_t)(tnext) * 128, bq)                             \
        }                                                                       \
        {                                                                       \
            int4v af[8], bf[4];                                                 \
            RD_A8(af, bp, kx0)                                                  \
            RD_B4(bf, bp, kx0)                                                  \
            MFMA32(af, bf)                                                      \
        }                                                                       \
        {                                                                       \
            int4v af[8], bf[4];                                                 \
            RD_A8(af, bp, kx1)                                                  \
            RD_B4(bf, bp, kx1)                                                  \
            MFMA32(af, bf)                                                      \
        }                                                                       \
        asm volatile("s_waitcnt lgkmcnt(0) vmcnt(0)" ::: "memory");             \
        __builtin_amdgcn_s_barrier();                                           \
    }

__global__ __launch_bounds__(512, 1) void gemm_kernel(const unsigned char* __restrict__ A,
                                                      const unsigned char* __restrict__ B,
                                                      const float* __restrict__ sx,
                                                      const float* __restrict__ scale,
                                                      const float* __restrict__ bias,
                                                      float* __restrict__ C) {
    __shared__ unsigned char sh[131072];  // 128 KiB -> 1 block/CU

    const int tid  = threadIdx.x;
    const int wv   = tid >> 6;      // 0..7
    const int lane = tid & 63;
    const int wm   = wv >> 2;       // 0..1 (M half)
    const int wn   = wv & 3;        // 0..3 (N quarter)

    // XCD swizzle (r7-verified, FETCH 275MB): 1376 = 8 xcd * 172; per-xcd
    // 4 bm x 43 bn, bm-inner (A-panels L2-resident, B streams L3).
    const int xcd = blockIdx.x & 7;
    const int l   = blockIdx.x >> 3;   // 0..171
    const int bm  = xcd * 4 + (l & 3);
    const int bn  = l >> 2;

    // fragment-read geometry (byte offsets)
    const int fr  = lane & 15;
    const int fq  = lane >> 4;
    const int swz = fr & 7;
    const int kx0 = (fq ^ swz) * 16;
    const int kx1 = ((4 + fq) ^ swz) * 16;

    // staging source offsets (inverse-swizzled granule)
    const int c0 = wv * 4;
    const int rl = lane >> 3;
    const int sg = (lane & 7) ^ rl;
    int soff[4];
#pragma unroll
    for (int i = 0; i < 4; ++i)
        soff[i] = ((c0 + i) * 8 + rl) * K_TOTAL + sg * 16;

    const unsigned char* aS = A + (size_t)bm * 256 * K_TOTAL;
    const unsigned char* bS = B + (size_t)bn * 256 * K_TOTAL;
    unsigned char* buf0 = sh;
    unsigned char* buf1 = sh + 65536;

    int4v acc[8][4] = {};

    // ---- prologue: tile 0 -> buf0 ----
    STAGE_A(aS, buf0)
    STAGE_B(bS, buf0)
    asm volatile("s_waitcnt vmcnt(0)" ::: "memory");
    __builtin_amdgcn_s_barrier();

    // ---- main loop, unrolled x2 for static buffer selection ----
#pragma unroll 1
    for (int u = 0; u < NT / 2; ++u) {
        TILE(buf0, buf1, 2 * u + 1)
        TILE(buf1, buf0, 2 * u + 2)
    }

    // ---- epilogue: y = acc * sx[row]*scale[col] + bias[col] ----
    const int crow0 = bm * 256 + wm * 128;
    const int ccol0 = bn * 256 + wn * 64;
    float scv[4], bsv[4];
#pragma unroll
    for (int n = 0; n < 4; ++n) {
        const int col = ccol0 + n * 16 + fr;
        scv[n] = scale[col];
        bsv[n] = bias[col];
    }
#pragma unroll
    for (int fm = 0; fm < 8; ++fm) {
#pragma unroll
        for (int j = 0; j < 4; ++j) {
            const int row = crow0 + fm * 16 + fq * 4 + j;
            const float sr = sx[row];
            float* cp = C + (size_t)row * N_TOTAL + ccol0 + fr;
#pragma unroll
            for (int n = 0; n < 4; ++n)
                cp[n * 16] = (float)acc[fm][n][j] * (sr * scv[n]) + bsv[n];
        }
    }
}

// ---------------- fallback (ws too small): tiled f32 vector GEMM ----------------

__global__ __launch_bounds__(256) void gemm_fallback(const float* __restrict__ x,
                                                     const int* __restrict__ w,
                                                     const float* __restrict__ scale,
                                                     const float* __restrict__ bias,
                                                     float* __restrict__ C) {
    bool is8 = false;
    for (int i = 0; i < 256; ++i) {
        int v = w[i];
        if (v < -127 || v > 127) { is8 = true; break; }
    }
    const signed char* w8 = (const signed char*)w;

    __shared__ float As[64][16];
    __shared__ float Bs[64][16];
    const int nbn = N_TOTAL / 64;
    const int bm = blockIdx.x / nbn;
    const int bn = blockIdx.x % nbn;
    const int tid = threadIdx.x;
    const int tx = tid & 15, ty = tid >> 4;

    float acc[4][4] = {};
    for (int kt = 0; kt < K_TOTAL; kt += 16) {
        for (int i = 0; i < 4; ++i) {
            int idx = tid + i * 256;
            int rr = idx >> 4, cc = idx & 15;
            As[rr][cc] = x[(size_t)(bm * 64 + rr) * K_TOTAL + kt + cc];
            size_t widx = (size_t)(bn * 64 + rr) * K_TOTAL + kt + cc;
            Bs[rr][cc] = is8 ? (float)w8[widx] : (float)w[widx];
        }
        __syncthreads();
        for (int kk = 0; kk < 16; ++kk) {
            float a[4], b[4];
            for (int i = 0; i < 4; ++i) a[i] = As[ty * 4 + i][kk];
            for (int j = 0; j < 4; ++j) b[j] = Bs[tx * 4 + j][kk];
            for (int i = 0; i < 4; ++i)
                for (int j = 0; j < 4; ++j) acc[i][j] += a[i] * b[j];
        }
        __syncthreads();
    }
    for (int j = 0; j < 4; ++j) {
        int col = bn * 64 + tx * 4 + j;
        float s = scale[col], bb = bias[col];
        for (int i = 0; i < 4; ++i) {
            int row = bm * 64 + ty * 4 + i;
            C[(size_t)row * N_TOTAL + col] = acc[i][j] * s + bb;
        }
    }
}

// ---------------- launch ----------------

extern "C" void kernel_launch(void* const* d_in, const int* in_sizes, int n_in,
                              void* d_out, int out_size, void* d_ws, size_t ws_size,
                              hipStream_t stream) {
    const float* x     = (const float*)d_in[0];
    const int*   wq    = (const int*)d_in[1];
    const float* scale = (const float*)d_in[2];
    const float* bias  = (const float*)d_in[3];
    float*       out   = (float*)d_out;

    const size_t x_bytes = (size_t)M_TOTAL * K_TOTAL;
    const size_t w_bytes = (size_t)N_TOTAL * K_TOTAL;
    const size_t need = x_bytes + w_bytes + M_TOTAL * sizeof(float);

    if (ws_size >= need) {
        signed char* xq = (signed char*)d_ws;
        signed char* wb = (signed char*)d_ws + x_bytes;
        float*       sx = (float*)((char*)d_ws + x_bytes + w_bytes);

        prep_kernel<<<M_TOTAL + 2048, 256, 0, stream>>>(x, wq, xq, wb, sx);
        dim3 grid(NBM * NBN);  // 1376
        gemm_kernel<<<grid, 512, 0, stream>>>((const unsigned char*)xq,
                                              (const unsigned char*)wb,
                                              sx, scale, bias, out);
    } else {
        dim3 grid((M_TOTAL / 64) * (N_TOTAL / 64));
        gemm_fallback<<<grid, 256, 0, stream>>>(x, wq, scale, bias, out);
    }
}

// Round 14
// 455.811 us; speedup vs baseline: 1.7032x; 1.7032x over previous
//
#include <hip/hip_runtime.h>
#include <hip/hip_bf16.h>
#include <stdint.h>

// QuantizedLinear: y = x @ (Wq * scale[:,None])^T + bias
// Round 14: 256x256 / BK=128 / 8 waves (2Mx4N) / ONE barrier per tile /
// counted vmcnt(4) / B TRIPLE-BUFFERED (2-tile prefetch depth) / A dbuf.
// r13 failed on pipeline depth: B staged 1-ahead + vmcnt(0) every tile ->
// 6000cyc/tile stage-latency stall (violated "never vmcnt(0) mid-loop").
// r7 had depth but a mid-tile serializing barrier. This cell has both fixes:
// LDS 160K (full CU): A[2] @ [0,64K), B[3] @ [64K,160K). Tile t reads
// A[t&1], B[t%3]; stages A(t+1)->A[(t+1)&1], B(t+2)->B[(t+2)%3].
// Tile: STAGE_A|STAGE_B; {RD12 K0; MFMA32}; {RD12 K1; MFMA32}; lgkm(0);
// vmcnt(4) [drains A(t+1), leaves B(t+2) flying]; barrier.
// WAR: both staged buffers' readers drained at t-1's lgkm(0)+barrier.
// RAW: A[t] drained by t-1's vmcnt(4) (1-tile cover, L2-resident A);
// B[t] staged at t-2 (2-tile cover vs L3/HBM tail). Tail: vmcnt(0).
// Floor: LDS 256KiB/tile @85B/cyc ~ 3084cyc vs MFMA 2611 -> ~250-310us GEMM.

#define M_TOTAL 8192
#define K_TOTAL 4096
#define N_TOTAL 11008
#define NT 32
#define NBM 32
#define NBN 43

typedef __attribute__((ext_vector_type(4))) int int4v;

// ---------------- fused prep: x row-quant + W unpack (r12 verbatim) ----------------

__global__ __launch_bounds__(256) void prep_kernel(const float* __restrict__ x,
                                                   const int* __restrict__ wq,
                                                   signed char* __restrict__ xq,
                                                   signed char* __restrict__ wb,
                                                   float* __restrict__ sx) {
    __shared__ float wm_[4];
    if (blockIdx.x < M_TOTAL) {
        const int row = blockIdx.x;
        const int tid = threadIdx.x;
        const float* xr = x + (size_t)row * K_TOTAL + tid * 16;

        float4 v0 = reinterpret_cast<const float4*>(xr)[0];
        float4 v1 = reinterpret_cast<const float4*>(xr)[1];
        float4 v2 = reinterpret_cast<const float4*>(xr)[2];
        float4 v3 = reinterpret_cast<const float4*>(xr)[3];

        float m = 0.f;
        m = fmaxf(m, fmaxf(fmaxf(fabsf(v0.x), fabsf(v0.y)), fmaxf(fabsf(v0.z), fabsf(v0.w))));
        m = fmaxf(m, fmaxf(fmaxf(fabsf(v1.x), fabsf(v1.y)), fmaxf(fabsf(v1.z), fabsf(v1.w))));
        m = fmaxf(m, fmaxf(fmaxf(fabsf(v2.x), fabsf(v2.y)), fmaxf(fabsf(v2.z), fabsf(v2.w))));
        m = fmaxf(m, fmaxf(fmaxf(fabsf(v3.x), fabsf(v3.y)), fmaxf(fabsf(v3.z), fabsf(v3.w))));

        for (int d = 1; d < 64; d <<= 1) m = fmaxf(m, __shfl_xor(m, d));
        if ((tid & 63) == 0) wm_[tid >> 6] = m;
        __syncthreads();
        m = fmaxf(fmaxf(wm_[0], wm_[1]), fmaxf(wm_[2], wm_[3]));

        const float inv = (m > 0.f) ? (127.f / m) : 0.f;
        if (tid == 0) sx[row] = (m > 0.f) ? (m / 127.f) : 0.f;

        float tmp[16] = {v0.x,v0.y,v0.z,v0.w, v1.x,v1.y,v1.z,v1.w,
                         v2.x,v2.y,v2.z,v2.w, v3.x,v3.y,v3.z,v3.w};
        int q[16];
#pragma unroll
        for (int i = 0; i < 16; ++i) {
            int t = __float2int_rn(tmp[i] * inv);
            q[i] = t > 127 ? 127 : (t < -127 ? -127 : t);
        }
        int4v o;
#pragma unroll
        for (int w = 0; w < 4; ++w)
            o[w] = (q[w*4] & 255) | ((q[w*4+1] & 255) << 8) |
                   ((q[w*4+2] & 255) << 16) | ((q[w*4+3] & 255) << 24);
        *reinterpret_cast<int4v*>(xq + (size_t)row * K_TOTAL + tid * 16) = o;
    } else {
        const int nitems = (int)(((size_t)N_TOTAL * K_TOTAL) / 16);
        bool is8 = false;
        for (int i = 0; i < 256; ++i) {
            int v = wq[i];
            if (v < -127 || v > 127) { is8 = true; break; }
        }
        const int nblk = gridDim.x - M_TOTAL;
        const int stride = nblk * blockDim.x;
        const int start = (blockIdx.x - M_TOTAL) * blockDim.x + threadIdx.x;
        if (!is8) {
            for (int i = start; i < nitems; i += stride) {
                const int* p = wq + (size_t)i * 16;
                int4v o;
#pragma unroll
                for (int w = 0; w < 4; ++w)
                    o[w] = (p[w*4] & 255) | ((p[w*4+1] & 255) << 8) |
                           ((p[w*4+2] & 255) << 16) | ((p[w*4+3] & 255) << 24);
                *reinterpret_cast<int4v*>(wb + (size_t)i * 16) = o;
            }
        } else {
            const int4v* in16 = reinterpret_cast<const int4v*>(wq);
            for (int i = start; i < nitems; i += stride)
                *reinterpret_cast<int4v*>(wb + (size_t)i * 16) = in16[i];
        }
    }
}

// ---------------- 256x256 i8 GEMM: single barrier, B triple-buffer ----------------

#define GLOAD16(g, l) __builtin_amdgcn_global_load_lds( \
    (const __attribute__((address_space(1))) void*)(g), \
    (__attribute__((address_space(3))) void*)(l), 16, 0, 0)

// LDS (bytes): A[2] at 0,32768; B[3] at 65536 + {0,32768,65536}.
// chunk = 8 rows = 1 KiB; wave wv stages chunks wv*4..wv*4+3 per operand.
// Swizzle: 16B granule g stored at g ^ (row&7); inverse applied on global src.

#define RD_A8(dst, base, KX)                                                    \
    _Pragma("unroll")                                                           \
    for (int i_ = 0; i_ < 8; ++i_)                                              \
        dst[i_] = *(const int4v*)((base) + (wm * 128 + i_ * 16 + fr) * 128 + (KX));
#define RD_B4(dst, base, KX)                                                    \
    _Pragma("unroll")                                                           \
    for (int n_ = 0; n_ < 4; ++n_)                                              \
        dst[n_] = *(const int4v*)((base) + (wn * 64 + n_ * 16 + fr) * 128 + (KX));
#define MFMA32(fa, fb)                                                          \
    __builtin_amdgcn_s_setprio(1);                                              \
    _Pragma("unroll")                                                           \
    for (int i_ = 0; i_ < 8; ++i_) {                                            \
        _Pragma("unroll")                                                       \
        for (int n_ = 0; n_ < 4; ++n_)                                          \
            acc[i_][n_] = __builtin_amdgcn_mfma_i32_16x16x64_i8(                \
                fa[i_], fb[n_], acc[i_][n_], 0, 0, 0);                          \
    }                                                                           \
    __builtin_amdgcn_s_setprio(0);
#define STAGE4(src, buf)                                                        \
    _Pragma("unroll")                                                           \
    for (int i_ = 0; i_ < 4; ++i_)                                              \
        GLOAD16((src) + soff[i_], (buf) + (c0 + i_) * 1024);

__global__ __launch_bounds__(512, 1) void gemm_kernel(const unsigned char* __restrict__ A,
                                                      const unsigned char* __restrict__ B,
                                                      const float* __restrict__ sx,
                                                      const float* __restrict__ scale,
                                                      const float* __restrict__ bias,
                                                      float* __restrict__ C) {
    __shared__ unsigned char sh[163840];  // 160 KiB: A dbuf 64K + B triple 96K

    const int tid  = threadIdx.x;
    const int wv   = tid >> 6;      // 0..7
    const int lane = tid & 63;
    const int wm   = wv >> 2;       // 0..1 (M half)
    const int wn   = wv & 3;        // 0..3 (N quarter)

    // XCD swizzle (r7-verified, FETCH 275MB): 1376 = 8 xcd * 172; per-xcd
    // 4 bm x 43 bn, bm-inner (A-panels L2-resident, B streams).
    const int xcd = blockIdx.x & 7;
    const int l   = blockIdx.x >> 3;   // 0..171
    const int bm  = xcd * 4 + (l & 3);
    const int bn  = l >> 2;

    // fragment-read geometry (byte offsets)
    const int fr  = lane & 15;
    const int fq  = lane >> 4;
    const int swz = fr & 7;
    const int kx0 = (fq ^ swz) * 16;
    const int kx1 = ((4 + fq) ^ swz) * 16;

    // staging source offsets (inverse-swizzled granule)
    const int c0 = wv * 4;
    const int rl = lane >> 3;
    const int sg = (lane & 7) ^ rl;
    int soff[4];
#pragma unroll
    for (int i = 0; i < 4; ++i)
        soff[i] = ((c0 + i) * 8 + rl) * K_TOTAL + sg * 16;

    const unsigned char* aS = A + (size_t)bm * 256 * K_TOTAL;
    const unsigned char* bS = B + (size_t)bn * 256 * K_TOTAL;
    unsigned char* shA = sh;          // A[p] = shA + p*32768
    unsigned char* shB = sh + 65536;  // B[q] = shB + q*32768

    int4v acc[8][4] = {};

    // ---- prologue: A(0)->A0, B(0)->B0, B(1)->B1 ----
    STAGE4(aS, shA)
    STAGE4(bS, shB)
    STAGE4(bS + 128, shB + 32768)
    asm volatile("s_waitcnt vmcnt(4)" ::: "memory");  // A(0),B(0) landed; B(1) flying
    __builtin_amdgcn_s_barrier();

    // ---- main loop: rotating B index (bc = t%3) ----
    int bc = 0;
#pragma unroll 1
    for (int t = 0; t < NT; ++t) {
        const int pa = t & 1;
        const int bn2 = (bc >= 1) ? (bc - 1) : (bc + 2);   // (t+2)%3
        const unsigned char* rdA = shA + (pa << 15);
        const unsigned char* rdB = shB + bc * 32768;
        unsigned char* stA = shA + ((pa ^ 1) << 15);
        unsigned char* stB = shB + bn2 * 32768;

        // stage A(t+1) [1-tile cover, L2-resident] and B(t+2) [2-tile cover]
        if (t + 1 < NT) { STAGE4(aS + (size_t)(t + 1) * 128, stA) }
        if (t + 2 < NT) { STAGE4(bS + (size_t)(t + 2) * 128, stB) }

        // K0 half: 12 frag reads + 32 MFMA (compiler inserts per-operand lgkm waits)
        {
            int4v af[8], bf[4];
            RD_A8(af, rdA, kx0)
            RD_B4(bf, rdB, kx0)
            MFMA32(af, bf)
        }
        // K1 half
        {
            int4v af[8], bf[4];
            RD_A8(af, rdA, kx1)
            RD_B4(bf, rdB, kx1)
            MFMA32(af, bf)
        }

        asm volatile("s_waitcnt lgkmcnt(0)" ::: "memory");  // all reads of rdA/rdB resolved
        if (t + 2 < NT) { asm volatile("s_waitcnt vmcnt(4)" ::: "memory"); }  // drain A(t+1), keep B(t+2)
        else            { asm volatile("s_waitcnt vmcnt(0)" ::: "memory"); }
        __builtin_amdgcn_s_barrier();

        bc = (bc >= 2) ? 0 : (bc + 1);
    }

    // ---- epilogue: y = acc * sx[row]*scale[col] + bias[col] ----
    const int crow0 = bm * 256 + wm * 128;
    const int ccol0 = bn * 256 + wn * 64;
    float scv[4], bsv[4];
#pragma unroll
    for (int n = 0; n < 4; ++n) {
        const int col = ccol0 + n * 16 + fr;
        scv[n] = scale[col];
        bsv[n] = bias[col];
    }
#pragma unroll
    for (int fm = 0; fm < 8; ++fm) {
#pragma unroll
        for (int j = 0; j < 4; ++j) {
            const int row = crow0 + fm * 16 + fq * 4 + j;
            const float sr = sx[row];
            float* cp = C + (size_t)row * N_TOTAL + ccol0 + fr;
#pragma unroll
            for (int n = 0; n < 4; ++n)
                cp[n * 16] = (float)acc[fm][n][j] * (sr * scv[n]) + bsv[n];
        }
    }
}

// ---------------- fallback (ws too small): tiled f32 vector GEMM ----------------

__global__ __launch_bounds__(256) void gemm_fallback(const float* __restrict__ x,
                                                     const int* __restrict__ w,
                                                     const float* __restrict__ scale,
                                                     const float* __restrict__ bias,
                                                     float* __restrict__ C) {
    bool is8 = false;
    for (int i = 0; i < 256; ++i) {
        int v = w[i];
        if (v < -127 || v > 127) { is8 = true; break; }
    }
    const signed char* w8 = (const signed char*)w;

    __shared__ float As[64][16];
    __shared__ float Bs[64][16];
    const int nbn = N_TOTAL / 64;
    const int bm = blockIdx.x / nbn;
    const int bn = blockIdx.x % nbn;
    const int tid = threadIdx.x;
    const int tx = tid & 15, ty = tid >> 4;

    float acc[4][4] = {};
    for (int kt = 0; kt < K_TOTAL; kt += 16) {
        for (int i = 0; i < 4; ++i) {
            int idx = tid + i * 256;
            int rr = idx >> 4, cc = idx & 15;
            As[rr][cc] = x[(size_t)(bm * 64 + rr) * K_TOTAL + kt + cc];
            size_t widx = (size_t)(bn * 64 + rr) * K_TOTAL + kt + cc;
            Bs[rr][cc] = is8 ? (float)w8[widx] : (float)w[widx];
        }
        __syncthreads();
        for (int kk = 0; kk < 16; ++kk) {
            float a[4], b[4];
            for (int i = 0; i < 4; ++i) a[i] = As[ty * 4 + i][kk];
            for (int j = 0; j < 4; ++j) b[j] = Bs[tx * 4 + j][kk];
            for (int i = 0; i < 4; ++i)
                for (int j = 0; j < 4; ++j) acc[i][j] += a[i] * b[j];
        }
        __syncthreads();
    }
    for (int j = 0; j < 4; ++j) {
        int col = bn * 64 + tx * 4 + j;
        float s = scale[col], bb = bias[col];
        for (int i = 0; i < 4; ++i) {
            int row = bm * 64 + ty * 4 + i;
            C[(size_t)row * N_TOTAL + col] = acc[i][j] * s + bb;
        }
    }
}

// ---------------- launch ----------------

extern "C" void kernel_launch(void* const* d_in, const int* in_sizes, int n_in,
                              void* d_out, int out_size, void* d_ws, size_t ws_size,
                              hipStream_t stream) {
    const float* x     = (const float*)d_in[0];
    const int*   wq    = (const int*)d_in[1];
    const float* scale = (const float*)d_in[2];
    const float* bias  = (const float*)d_in[3];
    float*       out   = (float*)d_out;

    const size_t x_bytes = (size_t)M_TOTAL * K_TOTAL;
    const size_t w_bytes = (size_t)N_TOTAL * K_TOTAL;
    const size_t need = x_bytes + w_bytes + M_TOTAL * sizeof(float);

    if (ws_size >= need) {
        signed char* xq = (signed char*)d_ws;
        signed char* wb = (signed char*)d_ws + x_bytes;
        float*       sx = (float*)((char*)d_ws + x_bytes + w_bytes);

        prep_kernel<<<M_TOTAL + 2048, 256, 0, stream>>>(x, wq, xq, wb, sx);
        dim3 grid(NBM * NBN);  // 1376
        gemm_kernel<<<grid, 512, 0, stream>>>((const unsigned char*)xq,
                                              (const unsigned char*)wb,
                                              sx, scale, bias, out);
    } else {
        dim3 grid((M_TOTAL / 64) * (N_TOTAL / 64));
        gemm_fallback<<<grid, 256, 0, stream>>>(x, wq, scale, bias, out);
    }
}